// Round 1
// baseline (237.070 us; speedup 1.0000x reference)
//
#include <hip/hip_runtime.h>
#include <stdint.h>

// Problem constants
#define SEQ   2048
#define EMB   1024
#define PROJ  1024
#define HEADS 16
#define HD    64
#define BATCH 2
#define MROWS (BATCH * SEQ)   // 4096

typedef __attribute__((ext_vector_type(8))) __bf16 bf16x8;
typedef __attribute__((ext_vector_type(4))) __bf16 bf16x4;
typedef __attribute__((ext_vector_type(4))) float  f32x4;

static __device__ __forceinline__ __bf16 f2b(float f) {
  union { float f; uint32_t u; } a; a.f = f;
  uint32_t r = a.u + 0x7FFFu + ((a.u >> 16) & 1u);
  union { uint16_t u; __bf16 b; } o; o.u = (uint16_t)(r >> 16);
  return o.b;
}

#define GLOAD_LDS16(gsrc, ldst)                                                \
  __builtin_amdgcn_global_load_lds(                                            \
      (const __attribute__((address_space(1))) void*)(gsrc),                   \
      (__attribute__((address_space(3))) void*)(ldst), 16, 0, 0)

// ---------------------------------------------------------------------------
// fp32 -> bf16 elementwise cast (vectorized 4/thread)
// ---------------------------------------------------------------------------
__global__ void cast_f32_bf16(const float* __restrict__ in,
                              __bf16* __restrict__ out, int n) {
  int i = (blockIdx.x * blockDim.x + threadIdx.x) * 4;
  if (i + 3 < n) {
    float4 v = *reinterpret_cast<const float4*>(in + i);
    bf16x4 o;
    o[0] = f2b(v.x); o[1] = f2b(v.y); o[2] = f2b(v.z); o[3] = f2b(v.w);
    *reinterpret_cast<bf16x4*>(out + i) = o;
  }
}

// ---------------------------------------------------------------------------
// Transpose + cast: T[n][k] = (bf16) W[k][n], 1024x1024, 32x32 LDS tiles.
// blockIdx.z selects which of the 4 weight matrices.
// ---------------------------------------------------------------------------
__global__ void transpose_cast(const float* __restrict__ W0, const float* __restrict__ W1,
                               const float* __restrict__ W2, const float* __restrict__ W3,
                               __bf16* __restrict__ T0, __bf16* __restrict__ T1,
                               __bf16* __restrict__ T2, __bf16* __restrict__ T3) {
  const float* W; __bf16* T;
  switch (blockIdx.z) {
    case 0: W = W0; T = T0; break;
    case 1: W = W1; T = T1; break;
    case 2: W = W2; T = T2; break;
    default: W = W3; T = T3; break;
  }
  __shared__ float tile[32][33];
  int k0 = blockIdx.x * 32, n0 = blockIdx.y * 32;
  int tx = threadIdx.x & 31, ty = threadIdx.x >> 5;  // 256 thr: ty 0..7
#pragma unroll
  for (int r = ty; r < 32; r += 8)
    tile[r][tx] = W[(size_t)(k0 + r) * 1024 + n0 + tx];
  __syncthreads();
#pragma unroll
  for (int r = ty; r < 32; r += 8)
    T[(size_t)(n0 + r) * 1024 + k0 + tx] = f2b(tile[tx][r]);
}

// ---------------------------------------------------------------------------
// bf16 GEMM, C = A[M,K] * B[K,N] with B given transposed (Bt[N][K]).
// 128x128 tile, BK=32, 256 threads = 4 waves in 2x2, 64x64 per wave.
// MFMA 16x16x32. Output fp32 or bf16.
// Fragment layout (verified m89/m91): A row = lane&15, k = 8*(lane>>4)+j;
// B col = lane&15, same k; D col = lane&15, row = 4*(lane>>4)+reg.
// ---------------------------------------------------------------------------
template <bool OUT_BF16>
__global__ __launch_bounds__(256) void gemm_bt(const __bf16* __restrict__ A,
                                               const __bf16* __restrict__ Bt,
                                               void* __restrict__ Cout,
                                               int M, int N, int K) {
  __shared__ __align__(16) __bf16 As[128 * 32];
  __shared__ __align__(16) __bf16 Bs[128 * 32];
  const int t = threadIdx.x;
  const int lane = t & 63, w = t >> 6;
  const int g = lane >> 4, l15 = lane & 15;
  const int m0 = blockIdx.x * 128, n0 = blockIdx.y * 128;
  const int wr = w >> 1, wc = w & 1;

  f32x4 acc[4][4];
#pragma unroll
  for (int i = 0; i < 4; i++)
#pragma unroll
    for (int j = 0; j < 4; j++) acc[i][j] = {0.f, 0.f, 0.f, 0.f};

  const int c0 = t;        // staging chunk ids (8 bf16 = 16B per chunk)
  const int c1 = t + 256;

  for (int k0 = 0; k0 < K; k0 += 32) {
    __syncthreads();
    // stage A tile [128][32] and Bt tile [128][32], linear LDS (gl_lds rule)
    GLOAD_LDS16(A + (size_t)(m0 + (c0 >> 2)) * K + k0 + (c0 & 3) * 8, As + c0 * 8);
    GLOAD_LDS16(A + (size_t)(m0 + (c1 >> 2)) * K + k0 + (c1 & 3) * 8, As + c1 * 8);
    GLOAD_LDS16(Bt + (size_t)(n0 + (c0 >> 2)) * K + k0 + (c0 & 3) * 8, Bs + c0 * 8);
    GLOAD_LDS16(Bt + (size_t)(n0 + (c1 >> 2)) * K + k0 + (c1 & 3) * 8, Bs + c1 * 8);
    __syncthreads();

    bf16x8 af[4], bfr[4];
#pragma unroll
    for (int mi = 0; mi < 4; mi++)
      af[mi] = *reinterpret_cast<const bf16x8*>(As + (wr * 64 + mi * 16 + l15) * 32 + g * 8);
#pragma unroll
    for (int ni = 0; ni < 4; ni++)
      bfr[ni] = *reinterpret_cast<const bf16x8*>(Bs + (wc * 64 + ni * 16 + l15) * 32 + g * 8);
#pragma unroll
    for (int mi = 0; mi < 4; mi++)
#pragma unroll
      for (int ni = 0; ni < 4; ni++)
        acc[mi][ni] = __builtin_amdgcn_mfma_f32_16x16x32_bf16(af[mi], bfr[ni], acc[mi][ni], 0, 0, 0);
  }

#pragma unroll
  for (int mi = 0; mi < 4; mi++)
#pragma unroll
    for (int ni = 0; ni < 4; ni++) {
      int row = m0 + wr * 64 + mi * 16 + g * 4;
      int col = n0 + wc * 64 + ni * 16 + l15;
#pragma unroll
      for (int r = 0; r < 4; r++) {
        float v = acc[mi][ni][r];
        if (OUT_BF16)
          ((__bf16*)Cout)[(size_t)(row + r) * N + col] = f2b(v);
        else
          ((float*)Cout)[(size_t)(row + r) * N + col] = v;
      }
    }
}

// ---------------------------------------------------------------------------
// Causal flash attention. Q,K,V,ctx all [4096][1024] bf16 (head h at col h*64).
// Grid (16 qtiles, 32 bh). 256 thr = 4 waves; wave owns 32 q-rows (QBLK=128).
// Swapped QK^T: D = K*Q^T so softmax row q = lane&15 (lane-local state).
// KVBLK=64. K/Q frags straight from global (L2-resident); V transposed to LDS.
// ---------------------------------------------------------------------------
__global__ __launch_bounds__(256) void attn_fwd(const __bf16* __restrict__ Q,
                                                const __bf16* __restrict__ K,
                                                const __bf16* __restrict__ V,
                                                __bf16* __restrict__ ctx) {
  const int qt = blockIdx.x;   // 0..15
  const int bh = blockIdx.y;   // 0..31
  const int b = bh >> 4, h = bh & 15;
  const int t = threadIdx.x, lane = t & 63, w = t >> 6;
  const int g = lane >> 4, l15 = lane & 15;
  const int q0 = qt * 128;
  const int qw = q0 + w * 32;          // wave's first q row
  const float scale = 0.125f;          // 1/sqrt(64)

  __shared__ __align__(16) __bf16 P_lds[4][32][72];  // per-wave P, padded
  __shared__ __align__(16) __bf16 Vt[64][72];        // V^T tile, padded

  const size_t bO = (size_t)b * SEQ * 1024 + (size_t)h * 64;
  const __bf16* Qg = Q + bO;
  const __bf16* Kg = K + bO;
  const __bf16* Vg = V + bO;

  // Q fragments (B-operand): qf[m][ks][j] = Q[qw+m*16+l15][ks*32+g*8+j]
  bf16x8 qf[2][2];
#pragma unroll
  for (int m = 0; m < 2; m++)
#pragma unroll
    for (int ks = 0; ks < 2; ks++)
      qf[m][ks] = *reinterpret_cast<const bf16x8*>(
          Qg + (size_t)(qw + m * 16 + l15) * 1024 + ks * 32 + g * 8);

  f32x4 acco[2][4];
#pragma unroll
  for (int m = 0; m < 2; m++)
#pragma unroll
    for (int nd = 0; nd < 4; nd++) acco[m][nd] = {0.f, 0.f, 0.f, 0.f};
  float mrun[2] = {-1e30f, -1e30f};
  float lrun[2] = {0.f, 0.f};

  const int kv_end = q0 + 128;
  const int q_last = qw + 31;

  for (int kv0 = 0; kv0 < kv_end; kv0 += 64) {
    __syncthreads();
    {  // stage V[kv0..+64][:] transposed into Vt[d][kv] (all 4 waves)
      int kvr = t & 63, cb = t >> 6;
      const __bf16* vr = Vg + (size_t)(kv0 + kvr) * 1024 + cb * 16;
      bf16x8 v0 = *reinterpret_cast<const bf16x8*>(vr);
      bf16x8 v1 = *reinterpret_cast<const bf16x8*>(vr + 8);
#pragma unroll
      for (int j = 0; j < 8; j++) Vt[cb * 16 + j][kvr] = v0[j];
#pragma unroll
      for (int j = 0; j < 8; j++) Vt[cb * 16 + 8 + j][kvr] = v1[j];
    }
    __syncthreads();

    if (kv0 <= q_last) {  // wave-uniform
      // ---- QK^T (swapped): accS[nb][m] = K_tile * Q^T, D[kv][q]
      f32x4 accS[4][2];
#pragma unroll
      for (int nb = 0; nb < 4; nb++)
#pragma unroll
        for (int m = 0; m < 2; m++) accS[nb][m] = {0.f, 0.f, 0.f, 0.f};
#pragma unroll
      for (int nb = 0; nb < 4; nb++) {
        const __bf16* kr = Kg + (size_t)(kv0 + nb * 16 + l15) * 1024;
        bf16x8 kf0 = *reinterpret_cast<const bf16x8*>(kr + g * 8);
        bf16x8 kf1 = *reinterpret_cast<const bf16x8*>(kr + 32 + g * 8);
#pragma unroll
        for (int m = 0; m < 2; m++) {
          accS[nb][m] = __builtin_amdgcn_mfma_f32_16x16x32_bf16(kf0, qf[m][0], accS[nb][m], 0, 0, 0);
          accS[nb][m] = __builtin_amdgcn_mfma_f32_16x16x32_bf16(kf1, qf[m][1], accS[nb][m], 0, 0, 0);
        }
      }
      // ---- mask + scale: kv = kv0+nb*16+g*4+r, q = qw+m*16+l15
#pragma unroll
      for (int nb = 0; nb < 4; nb++)
#pragma unroll
        for (int m = 0; m < 2; m++)
#pragma unroll
          for (int r = 0; r < 4; r++) {
            int kvi = kv0 + nb * 16 + g * 4 + r;
            int qi = qw + m * 16 + l15;
            float s = accS[nb][m][r] * scale;
            accS[nb][m][r] = (kvi <= qi) ? s : -1e30f;
          }
      // ---- online softmax (row = lane's own q = m*16+l15)
#pragma unroll
      for (int m = 0; m < 2; m++) {
        float pmax = -1e30f;
#pragma unroll
        for (int nb = 0; nb < 4; nb++)
#pragma unroll
          for (int r = 0; r < 4; r++) pmax = fmaxf(pmax, accS[nb][m][r]);
        pmax = fmaxf(pmax, __shfl_xor(pmax, 16));
        pmax = fmaxf(pmax, __shfl_xor(pmax, 32));
        float mnew = fmaxf(mrun[m], pmax);
        float corr = __expf(mrun[m] - mnew);
        mrun[m] = mnew;
        float lsum = 0.f;
#pragma unroll
        for (int nb = 0; nb < 4; nb++) {
          bf16x4 pk;
#pragma unroll
          for (int r = 0; r < 4; r++) {
            float p = __expf(accS[nb][m][r] - mnew);
            lsum += p;
            pk[r] = f2b(p);
          }
          *reinterpret_cast<bf16x4*>(&P_lds[w][m * 16 + l15][nb * 16 + g * 4]) = pk;
        }
        lsum += __shfl_xor(lsum, 16);
        lsum += __shfl_xor(lsum, 32);
        lrun[m] = lrun[m] * corr + lsum;
        // rescale existing O rows (row q_local = g*4+r, state held at l15=q_local)
#pragma unroll
        for (int r = 0; r < 4; r++) {
          float cr = __shfl(corr, (g << 4) + (g << 2) + r);
#pragma unroll
          for (int nd = 0; nd < 4; nd++) acco[m][nd][r] *= cr;
        }
      }
      // ---- PV: O[q][d] += P[q][kv] * V[kv][d]
#pragma unroll
      for (int m = 0; m < 2; m++) {
        bf16x8 pa0 = *reinterpret_cast<const bf16x8*>(&P_lds[w][m * 16 + l15][g * 8]);
        bf16x8 pa1 = *reinterpret_cast<const bf16x8*>(&P_lds[w][m * 16 + l15][32 + g * 8]);
#pragma unroll
        for (int nd = 0; nd < 4; nd++) {
          bf16x8 vb0 = *reinterpret_cast<const bf16x8*>(&Vt[nd * 16 + l15][g * 8]);
          bf16x8 vb1 = *reinterpret_cast<const bf16x8*>(&Vt[nd * 16 + l15][32 + g * 8]);
          acco[m][nd] = __builtin_amdgcn_mfma_f32_16x16x32_bf16(pa0, vb0, acco[m][nd], 0, 0, 0);
          acco[m][nd] = __builtin_amdgcn_mfma_f32_16x16x32_bf16(pa1, vb1, acco[m][nd], 0, 0, 0);
        }
      }
    }
  }

  // epilogue: ctx = O / l
  __bf16* Cg = ctx + bO;
#pragma unroll
  for (int m = 0; m < 2; m++) {
    float inv = 1.0f / lrun[m];
#pragma unroll
    for (int r = 0; r < 4; r++) {
      float ir = __shfl(inv, (g << 4) + (g << 2) + r);
      int qrow = qw + m * 16 + g * 4 + r;
#pragma unroll
      for (int nd = 0; nd < 4; nd++)
        Cg[(size_t)qrow * 1024 + nd * 16 + l15] = f2b(acco[m][nd][r] * ir);
    }
  }
}

// ---------------------------------------------------------------------------
extern "C" void kernel_launch(void* const* d_in, const int* in_sizes, int n_in,
                              void* d_out, int out_size, void* d_ws, size_t ws_size,
                              hipStream_t stream) {
  const float* X  = (const float*)d_in[0];
  const float* Wq = (const float*)d_in[1];
  const float* Wk = (const float*)d_in[2];
  const float* Wv = (const float*)d_in[3];
  const float* Wo = (const float*)d_in[4];
  float* out = (float*)d_out;

  uint8_t* ws = (uint8_t*)d_ws;
  size_t off = 0;
  const size_t actBytes = (size_t)MROWS * 1024 * 2;  // 8 MB
  const size_t wBytes   = (size_t)1024 * 1024 * 2;   // 2 MB
  __bf16* Xb  = (__bf16*)(ws + off); off += actBytes;
  __bf16* WqT = (__bf16*)(ws + off); off += wBytes;
  __bf16* WkT = (__bf16*)(ws + off); off += wBytes;
  __bf16* WvT = (__bf16*)(ws + off); off += wBytes;
  __bf16* WoT = (__bf16*)(ws + off); off += wBytes;
  __bf16* Qb  = (__bf16*)(ws + off); off += actBytes;
  __bf16* Kb  = (__bf16*)(ws + off); off += actBytes;
  __bf16* Vb  = (__bf16*)(ws + off); off += actBytes;
  __bf16* Cb  = (__bf16*)(ws + off); off += actBytes;

  // 1) casts
  cast_f32_bf16<<<dim3(MROWS * 1024 / 4 / 256), dim3(256), 0, stream>>>(X, Xb, MROWS * 1024);
  transpose_cast<<<dim3(32, 32, 4), dim3(256), 0, stream>>>(Wq, Wk, Wv, Wo, WqT, WkT, WvT, WoT);

  // 2) QKV projections
  dim3 ggrid(MROWS / 128, PROJ / 128);
  gemm_bt<true><<<ggrid, dim3(256), 0, stream>>>(Xb, WqT, Qb, MROWS, PROJ, EMB);
  gemm_bt<true><<<ggrid, dim3(256), 0, stream>>>(Xb, WkT, Kb, MROWS, PROJ, EMB);
  gemm_bt<true><<<ggrid, dim3(256), 0, stream>>>(Xb, WvT, Vb, MROWS, PROJ, EMB);

  // 3) causal flash attention
  attn_fwd<<<dim3(SEQ / 128, BATCH * HEADS), dim3(256), 0, stream>>>(Qb, Kb, Vb, Cb);

  // 4) output projection (fp32 out)
  gemm_bt<false><<<ggrid, dim3(256), 0, stream>>>(Cb, WoT, out, MROWS, PROJ, PROJ);
}

// Round 2
// 158.633 us; speedup vs baseline: 1.4945x; 1.4945x over previous
//
#include <hip/hip_runtime.h>
#include <stdint.h>

// Problem constants
#define SEQ   2048
#define EMB   1024
#define PROJ  1024
#define HEADS 16
#define HD    64
#define BATCH 2
#define MROWS (BATCH * SEQ)   // 4096
#define QKVN  3072            // fused QKV output width

typedef __attribute__((ext_vector_type(8))) __bf16 bf16x8;
typedef __attribute__((ext_vector_type(4))) __bf16 bf16x4;
typedef __attribute__((ext_vector_type(4))) float  f32x4;

static __device__ __forceinline__ __bf16 f2b(float f) {
  union { float f; uint32_t u; } a; a.f = f;
  uint32_t r = a.u + 0x7FFFu + ((a.u >> 16) & 1u);
  union { uint16_t u; __bf16 b; } o; o.u = (uint16_t)(r >> 16);
  return o.b;
}

#define GLOAD_LDS16(gsrc, ldst)                                                \
  __builtin_amdgcn_global_load_lds(                                            \
      (const __attribute__((address_space(1))) void*)(gsrc),                   \
      (__attribute__((address_space(3))) void*)(ldst), 16, 0, 0)

// ---------------------------------------------------------------------------
// fp32 -> bf16 elementwise cast (vectorized 4/thread)
// ---------------------------------------------------------------------------
__global__ void cast_f32_bf16(const float* __restrict__ in,
                              __bf16* __restrict__ out, int n) {
  int i = (blockIdx.x * blockDim.x + threadIdx.x) * 4;
  if (i + 3 < n) {
    float4 v = *reinterpret_cast<const float4*>(in + i);
    bf16x4 o;
    o[0] = f2b(v.x); o[1] = f2b(v.y); o[2] = f2b(v.z); o[3] = f2b(v.w);
    *reinterpret_cast<bf16x4*>(out + i) = o;
  }
}

// ---------------------------------------------------------------------------
// Transpose + cast the 4 weight matrices. z=0..2 -> rows z*1024.. of WqkvT,
// z=3 -> WoT. T[n][k] = (bf16) W[k][n].
// ---------------------------------------------------------------------------
__global__ void transpose_cast(const float* __restrict__ W0, const float* __restrict__ W1,
                               const float* __restrict__ W2, const float* __restrict__ W3,
                               __bf16* __restrict__ Tqkv, __bf16* __restrict__ To) {
  const float* W; __bf16* T;
  switch (blockIdx.z) {
    case 0: W = W0; T = Tqkv;                       break;
    case 1: W = W1; T = Tqkv + (size_t)1024 * 1024; break;
    case 2: W = W2; T = Tqkv + (size_t)2048 * 1024; break;
    default: W = W3; T = To;                        break;
  }
  __shared__ float tile[32][33];
  int k0 = blockIdx.x * 32, n0 = blockIdx.y * 32;
  int tx = threadIdx.x & 31, ty = threadIdx.x >> 5;  // 256 thr: ty 0..7
#pragma unroll
  for (int r = ty; r < 32; r += 8)
    tile[r][tx] = W[(size_t)(k0 + r) * 1024 + n0 + tx];
  __syncthreads();
#pragma unroll
  for (int r = ty; r < 32; r += 8)
    T[(size_t)(n0 + r) * 1024 + k0 + tx] = f2b(tile[tx][r]);
}

// ---------------------------------------------------------------------------
// bf16 GEMM, C = A[M,K] * Bt^T (Bt[N][K]). Tile BM x 128, BK=32.
// 256 thr = 4 waves in 2x2; wave tile (BM/2) x 64. MFMA 16x16x32.
// SCALE_Q: multiply output by 0.125 when col < 1024 (attention Q pre-scale).
// ---------------------------------------------------------------------------
template <int BM, bool OUT_BF16, bool SCALE_Q>
__global__ __launch_bounds__(256) void gemm_bt(const __bf16* __restrict__ A,
                                               const __bf16* __restrict__ Bt,
                                               void* __restrict__ Cout,
                                               int M, int N, int K) {
  constexpr int MI = BM / 32;  // m-frags per wave
  __shared__ __align__(16) __bf16 As[BM * 32];
  __shared__ __align__(16) __bf16 Bs[128 * 32];
  const int t = threadIdx.x;
  const int lane = t & 63, w = t >> 6;
  const int g = lane >> 4, l15 = lane & 15;
  const int m0 = blockIdx.x * BM, n0 = blockIdx.y * 128;
  const int wr = w >> 1, wc = w & 1;

  f32x4 acc[MI][4];
#pragma unroll
  for (int i = 0; i < MI; i++)
#pragma unroll
    for (int j = 0; j < 4; j++) acc[i][j] = {0.f, 0.f, 0.f, 0.f};

  for (int k0 = 0; k0 < K; k0 += 32) {
    __syncthreads();
#pragma unroll
    for (int c = t; c < BM * 4; c += 256)  // A tile [BM][32]
      GLOAD_LDS16(A + (size_t)(m0 + (c >> 2)) * K + k0 + (c & 3) * 8, As + c * 8);
#pragma unroll
    for (int c = t; c < 512; c += 256)     // Bt tile [128][32]
      GLOAD_LDS16(Bt + (size_t)(n0 + (c >> 2)) * K + k0 + (c & 3) * 8, Bs + c * 8);
    __syncthreads();

    bf16x8 af[MI], bfr[4];
#pragma unroll
    for (int mi = 0; mi < MI; mi++)
      af[mi] = *reinterpret_cast<const bf16x8*>(As + (wr * (BM / 2) + mi * 16 + l15) * 32 + g * 8);
#pragma unroll
    for (int ni = 0; ni < 4; ni++)
      bfr[ni] = *reinterpret_cast<const bf16x8*>(Bs + (wc * 64 + ni * 16 + l15) * 32 + g * 8);
#pragma unroll
    for (int mi = 0; mi < MI; mi++)
#pragma unroll
      for (int ni = 0; ni < 4; ni++)
        acc[mi][ni] = __builtin_amdgcn_mfma_f32_16x16x32_bf16(af[mi], bfr[ni], acc[mi][ni], 0, 0, 0);
  }

#pragma unroll
  for (int mi = 0; mi < MI; mi++)
#pragma unroll
    for (int ni = 0; ni < 4; ni++) {
      int row = m0 + wr * (BM / 2) + mi * 16 + g * 4;
      int col = n0 + wc * 64 + ni * 16 + l15;
#pragma unroll
      for (int r = 0; r < 4; r++) {
        float v = acc[mi][ni][r];
        if (SCALE_Q && col < 1024) v *= 0.125f;
        if (OUT_BF16)
          ((__bf16*)Cout)[(size_t)(row + r) * N + col] = f2b(v);
        else
          ((float*)Cout)[(size_t)(row + r) * N + col] = v;
      }
    }
}

// ---------------------------------------------------------------------------
// V pre-transpose: Vt[(bh*64 + d)*2048 + s] = QKV[b][s][2048 + h*64 + d].
// grid (SEQ/64, BATCH*HEADS), 256 thr. Loads bf16x8 (L2), stores coalesced.
// ---------------------------------------------------------------------------
__global__ void v_transpose(const __bf16* __restrict__ QKV, __bf16* __restrict__ Vt) {
  const int sb = blockIdx.x, bh = blockIdx.y;
  const int lane = threadIdx.x & 63, w = threadIdx.x >> 6;
  const int b = bh >> 4, h = bh & 15;
  const int s = sb * 64 + lane;
  const __bf16* src = QKV + (size_t)b * SEQ * QKVN + (size_t)s * QKVN + 2048 + h * 64 + w * 16;
  bf16x8 v0 = *reinterpret_cast<const bf16x8*>(src);
  bf16x8 v1 = *reinterpret_cast<const bf16x8*>(src + 8);
  __bf16* dst = Vt + ((size_t)bh * 64 + w * 16) * 2048 + s;
#pragma unroll
  for (int j = 0; j < 8; j++) dst[(size_t)j * 2048] = v0[j];
#pragma unroll
  for (int j = 0; j < 8; j++) dst[(size_t)(8 + j) * 2048] = v1[j];
}

// ---------------------------------------------------------------------------
// Causal flash attention, barrier-free. Q,K read from fused QKV [4096][3072]
// (Q pre-scaled by 1/8 in the GEMM); V from Vt [bh][64][2048]; out ctx
// [4096][1024] bf16. Grid (16 pair-blocks, 32 bh), 256 thr = 4 independent
// waves. Waves 0,1 -> qtile pi; waves 2,3 -> qtile 31-pi (64 rows each tile,
// 32 rows per wave) => uniform 66 KV-tile-units per block.
// Swapped QK^T: D = K*Q^T so softmax row q = lane&15 (lane-local state).
// ---------------------------------------------------------------------------
__global__ __launch_bounds__(256) void attn_fwd(const __bf16* __restrict__ QKV,
                                                const __bf16* __restrict__ Vt,
                                                __bf16* __restrict__ ctx) {
  const int pi = blockIdx.x;   // 0..15
  const int bh = blockIdx.y;   // 0..31
  const int b = bh >> 4, h = bh & 15;
  const int t = threadIdx.x, lane = t & 63, w = t >> 6;
  const int g = lane >> 4, l15 = lane & 15;
  const int tile = (w < 2) ? pi : (31 - pi);   // qtile of 64 rows
  const int qw = tile * 64 + (w & 1) * 32;     // wave's first q row

  __shared__ __align__(16) __bf16 P_lds[4][32][72];  // per-wave P, padded

  const __bf16* Qg  = QKV + (size_t)b * SEQ * QKVN + h * 64;
  const __bf16* Kg  = QKV + (size_t)b * SEQ * QKVN + 1024 + h * 64;
  const __bf16* VtH = Vt + (size_t)bh * 64 * 2048;

  // Q fragments (B-operand): qf[m][ks][j] = Q[qw+m*16+l15][ks*32+g*8+j]
  bf16x8 qf[2][2];
#pragma unroll
  for (int m = 0; m < 2; m++)
#pragma unroll
    for (int ks = 0; ks < 2; ks++)
      qf[m][ks] = *reinterpret_cast<const bf16x8*>(
          Qg + (size_t)(qw + m * 16 + l15) * QKVN + ks * 32 + g * 8);

  f32x4 acco[2][4];
#pragma unroll
  for (int m = 0; m < 2; m++)
#pragma unroll
    for (int nd = 0; nd < 4; nd++) acco[m][nd] = {0.f, 0.f, 0.f, 0.f};
  float mrun[2] = {-1e30f, -1e30f};
  float lrun[2] = {0.f, 0.f};

  const int ntile = tile + 1;
  for (int it = 0; it < ntile; ++it) {
    const int kv0 = it * 64;
    const bool full = (kv0 + 63 <= qw);  // wave-uniform

    // V fragments (issue early; overlap with QK^T + softmax)
    bf16x8 vb[4][2];
#pragma unroll
    for (int nd = 0; nd < 4; nd++)
#pragma unroll
      for (int ks = 0; ks < 2; ks++)
        vb[nd][ks] = *reinterpret_cast<const bf16x8*>(
            VtH + (size_t)(nd * 16 + l15) * 2048 + kv0 + ks * 32 + g * 8);

    // ---- QK^T (swapped): accS[nb][m] = K_tile * Q^T, D[kv][q]
    f32x4 accS[4][2];
#pragma unroll
    for (int nb = 0; nb < 4; nb++)
#pragma unroll
      for (int m = 0; m < 2; m++) accS[nb][m] = {0.f, 0.f, 0.f, 0.f};
#pragma unroll
    for (int nb = 0; nb < 4; nb++) {
      const __bf16* kr = Kg + (size_t)(kv0 + nb * 16 + l15) * QKVN;
      bf16x8 kf0 = *reinterpret_cast<const bf16x8*>(kr + g * 8);
      bf16x8 kf1 = *reinterpret_cast<const bf16x8*>(kr + 32 + g * 8);
#pragma unroll
      for (int m = 0; m < 2; m++) {
        accS[nb][m] = __builtin_amdgcn_mfma_f32_16x16x32_bf16(kf0, qf[m][0], accS[nb][m], 0, 0, 0);
        accS[nb][m] = __builtin_amdgcn_mfma_f32_16x16x32_bf16(kf1, qf[m][1], accS[nb][m], 0, 0, 0);
      }
    }
    // ---- causal mask (only diagonal tiles): kv = kv0+nb*16+g*4+r, q = qw+m*16+l15
    if (!full) {
#pragma unroll
      for (int nb = 0; nb < 4; nb++)
#pragma unroll
        for (int m = 0; m < 2; m++)
#pragma unroll
          for (int r = 0; r < 4; r++) {
            int kvi = kv0 + nb * 16 + g * 4 + r;
            int qi = qw + m * 16 + l15;
            if (kvi > qi) accS[nb][m][r] = -1e30f;
          }
    }
    // ---- online softmax (row = lane's own q = m*16+l15)
#pragma unroll
    for (int m = 0; m < 2; m++) {
      float pmax = -1e30f;
#pragma unroll
      for (int nb = 0; nb < 4; nb++)
#pragma unroll
        for (int r = 0; r < 4; r++) pmax = fmaxf(pmax, accS[nb][m][r]);
      pmax = fmaxf(pmax, __shfl_xor(pmax, 16));
      pmax = fmaxf(pmax, __shfl_xor(pmax, 32));
      float mnew = fmaxf(mrun[m], pmax);
      float corr = __expf(mrun[m] - mnew);
      mrun[m] = mnew;
      float lsum = 0.f;
#pragma unroll
      for (int nb = 0; nb < 4; nb++) {
        bf16x4 pk;
#pragma unroll
        for (int r = 0; r < 4; r++) {
          float p = __expf(accS[nb][m][r] - mnew);
          lsum += p;
          pk[r] = f2b(p);
        }
        *reinterpret_cast<bf16x4*>(&P_lds[w][m * 16 + l15][nb * 16 + g * 4]) = pk;
      }
      lsum += __shfl_xor(lsum, 16);
      lsum += __shfl_xor(lsum, 32);
      lrun[m] = lrun[m] * corr + lsum;
      // rescale existing O rows (row q_local = g*4+r, state held at l15=q_local)
#pragma unroll
      for (int r = 0; r < 4; r++) {
        float cr = __shfl(corr, (g << 4) + (g << 2) + r);
#pragma unroll
        for (int nd = 0; nd < 4; nd++) acco[m][nd][r] *= cr;
      }
    }
    // ---- PV: O[q][d] += P[q][kv] * V[kv][d]
#pragma unroll
    for (int m = 0; m < 2; m++) {
      bf16x8 pa0 = *reinterpret_cast<const bf16x8*>(&P_lds[w][m * 16 + l15][g * 8]);
      bf16x8 pa1 = *reinterpret_cast<const bf16x8*>(&P_lds[w][m * 16 + l15][32 + g * 8]);
#pragma unroll
      for (int nd = 0; nd < 4; nd++) {
        acco[m][nd] = __builtin_amdgcn_mfma_f32_16x16x32_bf16(pa0, vb[nd][0], acco[m][nd], 0, 0, 0);
        acco[m][nd] = __builtin_amdgcn_mfma_f32_16x16x32_bf16(pa1, vb[nd][1], acco[m][nd], 0, 0, 0);
      }
    }
  }

  // epilogue: ctx = O / l
  __bf16* Cg = ctx + (size_t)b * SEQ * 1024 + h * 64;
#pragma unroll
  for (int m = 0; m < 2; m++) {
    float inv = 1.0f / lrun[m];
#pragma unroll
    for (int r = 0; r < 4; r++) {
      float ir = __shfl(inv, (g << 4) + (g << 2) + r);
      int qrow = qw + m * 16 + g * 4 + r;
#pragma unroll
      for (int nd = 0; nd < 4; nd++)
        Cg[(size_t)qrow * 1024 + nd * 16 + l15] = f2b(acco[m][nd][r] * ir);
    }
  }
}

// ---------------------------------------------------------------------------
extern "C" void kernel_launch(void* const* d_in, const int* in_sizes, int n_in,
                              void* d_out, int out_size, void* d_ws, size_t ws_size,
                              hipStream_t stream) {
  const float* X  = (const float*)d_in[0];
  const float* Wq = (const float*)d_in[1];
  const float* Wk = (const float*)d_in[2];
  const float* Wv = (const float*)d_in[3];
  const float* Wo = (const float*)d_in[4];
  float* out = (float*)d_out;

  uint8_t* ws = (uint8_t*)d_ws;
  size_t off = 0;
  const size_t actBytes = (size_t)MROWS * 1024 * 2;          // 8 MB
  __bf16* Xb    = (__bf16*)(ws + off); off += actBytes;      // freed after QKV gemm
  __bf16* WqkvT = (__bf16*)(ws + off); off += (size_t)QKVN * 1024 * 2;
  __bf16* WoT   = (__bf16*)(ws + off); off += (size_t)1024 * 1024 * 2;
  __bf16* QKV   = (__bf16*)(ws + off); off += (size_t)MROWS * QKVN * 2;
  __bf16* Vt    = (__bf16*)(ws + off); off += actBytes;
  __bf16* Cb    = Xb;  // alias: X dead after QKV projection

  // 1) casts
  cast_f32_bf16<<<dim3(MROWS * 1024 / 4 / 256), dim3(256), 0, stream>>>(X, Xb, MROWS * 1024);
  transpose_cast<<<dim3(32, 32, 4), dim3(256), 0, stream>>>(Wq, Wk, Wv, Wo, WqkvT, WoT);

  // 2) fused QKV projection (Q pre-scaled by 1/8)
  gemm_bt<64, true, true><<<dim3(MROWS / 64, QKVN / 128), dim3(256), 0, stream>>>(
      Xb, WqkvT, QKV, MROWS, QKVN, EMB);

  // 3) V pre-transpose, then causal flash attention (barrier-free)
  v_transpose<<<dim3(SEQ / 64, BATCH * HEADS), dim3(256), 0, stream>>>(QKV, Vt);
  attn_fwd<<<dim3(16, BATCH * HEADS), dim3(256), 0, stream>>>(QKV, Vt, Cb);

  // 4) output projection (fp32 out)
  gemm_bt<64, false, false><<<dim3(MROWS / 64, PROJ / 128), dim3(256), 0, stream>>>(
      Cb, WoT, out, MROWS, PROJ, PROJ);
}

// Round 3
// 140.977 us; speedup vs baseline: 1.6816x; 1.1252x over previous
//
#include <hip/hip_runtime.h>
#include <stdint.h>

// Problem constants
#define SEQ   2048
#define EMB   1024
#define PROJ  1024
#define HEADS 16
#define HD    64
#define BATCH 2
#define MROWS (BATCH * SEQ)   // 4096
#define QKVN  3072            // fused QKV output width

typedef __attribute__((ext_vector_type(8))) __bf16 bf16x8;
typedef __attribute__((ext_vector_type(4))) __bf16 bf16x4;
typedef __attribute__((ext_vector_type(4))) float  f32x4;

static __device__ __forceinline__ __bf16 f2b(float f) {
  union { float f; uint32_t u; } a; a.f = f;
  uint32_t r = a.u + 0x7FFFu + ((a.u >> 16) & 1u);
  union { uint16_t u; __bf16 b; } o; o.u = (uint16_t)(r >> 16);
  return o.b;
}

#define GLOAD_LDS16(gsrc, ldst)                                                \
  __builtin_amdgcn_global_load_lds(                                            \
      (const __attribute__((address_space(1))) void*)(gsrc),                   \
      (__attribute__((address_space(3))) void*)(ldst), 16, 0, 0)

// ---------------------------------------------------------------------------
// fp32 -> bf16 elementwise cast (vectorized 4/thread)
// ---------------------------------------------------------------------------
__global__ void cast_f32_bf16(const float* __restrict__ in,
                              __bf16* __restrict__ out, int n) {
  int i = (blockIdx.x * blockDim.x + threadIdx.x) * 4;
  if (i + 3 < n) {
    float4 v = *reinterpret_cast<const float4*>(in + i);
    bf16x4 o;
    o[0] = f2b(v.x); o[1] = f2b(v.y); o[2] = f2b(v.z); o[3] = f2b(v.w);
    *reinterpret_cast<bf16x4*>(out + i) = o;
  }
}

// ---------------------------------------------------------------------------
// Transpose + cast the 4 weight matrices. z=0..2 -> rows z*1024.. of WqkvT,
// z=3 -> WoT. T[n][k] = (bf16) W[k][n].
// ---------------------------------------------------------------------------
__global__ void transpose_cast(const float* __restrict__ W0, const float* __restrict__ W1,
                               const float* __restrict__ W2, const float* __restrict__ W3,
                               __bf16* __restrict__ Tqkv, __bf16* __restrict__ To) {
  const float* W; __bf16* T;
  switch (blockIdx.z) {
    case 0: W = W0; T = Tqkv;                       break;
    case 1: W = W1; T = Tqkv + (size_t)1024 * 1024; break;
    case 2: W = W2; T = Tqkv + (size_t)2048 * 1024; break;
    default: W = W3; T = To;                        break;
  }
  __shared__ float tile[32][33];
  int k0 = blockIdx.x * 32, n0 = blockIdx.y * 32;
  int tx = threadIdx.x & 31, ty = threadIdx.x >> 5;  // 256 thr: ty 0..7
#pragma unroll
  for (int r = ty; r < 32; r += 8)
    tile[r][tx] = W[(size_t)(k0 + r) * 1024 + n0 + tx];
  __syncthreads();
#pragma unroll
  for (int r = ty; r < 32; r += 8)
    T[(size_t)(n0 + r) * 1024 + k0 + tx] = f2b(tile[tx][r]);
}

// ---------------------------------------------------------------------------
// bf16 GEMM, C = A[M,K] * Bt^T (Bt[N][K]). Tile BM x 128, BK=32.
// 256 thr = 4 waves in 2x2; wave tile (BM/2) x 64. MFMA 16x16x32.
// SCALE_Q: multiply output by 0.125 when col < 1024 (attention Q pre-scale).
// ---------------------------------------------------------------------------
template <int BM, bool OUT_BF16, bool SCALE_Q>
__global__ __launch_bounds__(256) void gemm_bt(const __bf16* __restrict__ A,
                                               const __bf16* __restrict__ Bt,
                                               void* __restrict__ Cout,
                                               int M, int N, int K) {
  constexpr int MI = BM / 32;  // m-frags per wave
  __shared__ __align__(16) __bf16 As[BM * 32];
  __shared__ __align__(16) __bf16 Bs[128 * 32];
  const int t = threadIdx.x;
  const int lane = t & 63, w = t >> 6;
  const int g = lane >> 4, l15 = lane & 15;
  const int m0 = blockIdx.x * BM, n0 = blockIdx.y * 128;
  const int wr = w >> 1, wc = w & 1;

  f32x4 acc[MI][4];
#pragma unroll
  for (int i = 0; i < MI; i++)
#pragma unroll
    for (int j = 0; j < 4; j++) acc[i][j] = {0.f, 0.f, 0.f, 0.f};

  for (int k0 = 0; k0 < K; k0 += 32) {
    __syncthreads();
#pragma unroll
    for (int c = t; c < BM * 4; c += 256)  // A tile [BM][32]
      GLOAD_LDS16(A + (size_t)(m0 + (c >> 2)) * K + k0 + (c & 3) * 8, As + c * 8);
#pragma unroll
    for (int c = t; c < 512; c += 256)     // Bt tile [128][32]
      GLOAD_LDS16(Bt + (size_t)(n0 + (c >> 2)) * K + k0 + (c & 3) * 8, Bs + c * 8);
    __syncthreads();

    bf16x8 af[MI], bfr[4];
#pragma unroll
    for (int mi = 0; mi < MI; mi++)
      af[mi] = *reinterpret_cast<const bf16x8*>(As + (wr * (BM / 2) + mi * 16 + l15) * 32 + g * 8);
#pragma unroll
    for (int ni = 0; ni < 4; ni++)
      bfr[ni] = *reinterpret_cast<const bf16x8*>(Bs + (wc * 64 + ni * 16 + l15) * 32 + g * 8);
#pragma unroll
    for (int mi = 0; mi < MI; mi++)
#pragma unroll
      for (int ni = 0; ni < 4; ni++)
        acc[mi][ni] = __builtin_amdgcn_mfma_f32_16x16x32_bf16(af[mi], bfr[ni], acc[mi][ni], 0, 0, 0);
  }

#pragma unroll
  for (int mi = 0; mi < MI; mi++)
#pragma unroll
    for (int ni = 0; ni < 4; ni++) {
      int row = m0 + wr * (BM / 2) + mi * 16 + g * 4;
      int col = n0 + wc * 64 + ni * 16 + l15;
#pragma unroll
      for (int r = 0; r < 4; r++) {
        float v = acc[mi][ni][r];
        if (SCALE_Q && col < 1024) v *= 0.125f;
        if (OUT_BF16)
          ((__bf16*)Cout)[(size_t)(row + r) * N + col] = f2b(v);
        else
          ((float*)Cout)[(size_t)(row + r) * N + col] = v;
      }
    }
}

// ---------------------------------------------------------------------------
// V pre-transpose: Vt[(bh*64 + d)*2048 + s] = QKV[b][s][2048 + h*64 + d].
// grid (SEQ/64, BATCH*HEADS), 256 thr. Loads bf16x8 (L2), stores coalesced.
// ---------------------------------------------------------------------------
__global__ void v_transpose(const __bf16* __restrict__ QKV, __bf16* __restrict__ Vt) {
  const int sb = blockIdx.x, bh = blockIdx.y;
  const int lane = threadIdx.x & 63, w = threadIdx.x >> 6;
  const int b = bh >> 4, h = bh & 15;
  const int s = sb * 64 + lane;
  const __bf16* src = QKV + (size_t)b * SEQ * QKVN + (size_t)s * QKVN + 2048 + h * 64 + w * 16;
  bf16x8 v0 = *reinterpret_cast<const bf16x8*>(src);
  bf16x8 v1 = *reinterpret_cast<const bf16x8*>(src + 8);
  __bf16* dst = Vt + ((size_t)bh * 64 + w * 16) * 2048 + s;
#pragma unroll
  for (int j = 0; j < 8; j++) dst[(size_t)j * 2048] = v0[j];
#pragma unroll
  for (int j = 0; j < 8; j++) dst[(size_t)(8 + j) * 2048] = v1[j];
}

// ---------------------------------------------------------------------------
// Causal flash attention, barrier-free, XCD-localized.
// Grid: 256 blocks x 512 thr (8 waves). Block id: xcd = id&7 owns heads
// bh = xcd*4 + ((id>>3)&3); pg = id>>5 selects 4 chunk-pairs.
// Wave w<4 -> chunk c = pg*4+(w&3); wave w>=4 -> c = 63-(pg*4+(w&3)).
// SIMD-paired waves (w, w+4) sum to exactly 33 KV-tile-units -> uniform.
// Chunk = 32 q rows. Swapped QK^T (D[kv][q], lane-local softmax state).
// K prefetched one KV-tile ahead; V issued at iteration top (consumed in PV).
// Q pre-scaled by 1/8 in the QKV GEMM.
// ---------------------------------------------------------------------------
__global__ __launch_bounds__(512, 2) void attn_fwd(const __bf16* __restrict__ QKV,
                                                   const __bf16* __restrict__ Vt,
                                                   __bf16* __restrict__ ctx) {
  const int id = blockIdx.x;
  const int within = id >> 3;
  const int bh = (id & 7) * 4 + (within & 3);
  const int pg = within >> 2;                    // 0..7
  const int b = bh >> 4, h = bh & 15;
  const int t = threadIdx.x, lane = t & 63, w = t >> 6;
  const int g = lane >> 4, l15 = lane & 15;
  const int jj = w & 3;
  const int c = (w < 4) ? (pg * 4 + jj) : (63 - pg * 4 - jj);
  const int qw = c * 32;                         // wave's first q row
  const int ntile = c / 2 + 1;

  __shared__ __align__(16) __bf16 P_lds[8][32][72];  // per-wave P, padded

  const __bf16* Qg  = QKV + (size_t)b * SEQ * QKVN + h * 64;
  const __bf16* Kg  = QKV + (size_t)b * SEQ * QKVN + 1024 + h * 64;
  const __bf16* VtH = Vt + (size_t)bh * 64 * 2048;

  // Q fragments (B-operand): qf[m][ks][j] = Q[qw+m*16+l15][ks*32+g*8+j]
  bf16x8 qf[2][2];
#pragma unroll
  for (int m = 0; m < 2; m++)
#pragma unroll
    for (int ks = 0; ks < 2; ks++)
      qf[m][ks] = *reinterpret_cast<const bf16x8*>(
          Qg + (size_t)(qw + m * 16 + l15) * QKVN + ks * 32 + g * 8);

  f32x4 acco[2][4];
#pragma unroll
  for (int m = 0; m < 2; m++)
#pragma unroll
    for (int nd = 0; nd < 4; nd++) acco[m][nd] = {0.f, 0.f, 0.f, 0.f};
  float mrun[2] = {-1e30f, -1e30f};
  float lrun[2] = {0.f, 0.f};

  // preload K fragments for tile 0
  bf16x8 kf[4][2], kn[4][2];
#pragma unroll
  for (int nb = 0; nb < 4; nb++) {
    const __bf16* kr = Kg + (size_t)(nb * 16 + l15) * QKVN + g * 8;
    kf[nb][0] = *reinterpret_cast<const bf16x8*>(kr);
    kf[nb][1] = *reinterpret_cast<const bf16x8*>(kr + 32);
  }

  for (int it = 0; it < ntile; ++it) {
    const int kv0 = it * 64;
    const bool last = (it == ntile - 1);

    // V fragments for current tile (consumed at the end, in PV)
    bf16x8 vb[4][2];
#pragma unroll
    for (int nd = 0; nd < 4; nd++)
#pragma unroll
      for (int ks = 0; ks < 2; ks++)
        vb[nd][ks] = *reinterpret_cast<const bf16x8*>(
            VtH + (size_t)(nd * 16 + l15) * 2048 + kv0 + ks * 32 + g * 8);

    // prefetch next tile's K fragments
    if (it + 1 < ntile) {
#pragma unroll
      for (int nb = 0; nb < 4; nb++) {
        const __bf16* kr = Kg + (size_t)(kv0 + 64 + nb * 16 + l15) * QKVN + g * 8;
        kn[nb][0] = *reinterpret_cast<const bf16x8*>(kr);
        kn[nb][1] = *reinterpret_cast<const bf16x8*>(kr + 32);
      }
    }

    // ---- QK^T (swapped): accS[nb][m] = K_tile * Q^T, D[kv][q]
    f32x4 accS[4][2];
#pragma unroll
    for (int nb = 0; nb < 4; nb++)
#pragma unroll
      for (int m = 0; m < 2; m++) accS[nb][m] = {0.f, 0.f, 0.f, 0.f};
#pragma unroll
    for (int nb = 0; nb < 4; nb++)
#pragma unroll
      for (int m = 0; m < 2; m++) {
        accS[nb][m] = __builtin_amdgcn_mfma_f32_16x16x32_bf16(kf[nb][0], qf[m][0], accS[nb][m], 0, 0, 0);
        accS[nb][m] = __builtin_amdgcn_mfma_f32_16x16x32_bf16(kf[nb][1], qf[m][1], accS[nb][m], 0, 0, 0);
      }

    // ---- causal mask (diagonal tile only): kv = kv0+nb*16+g*4+r, q = qw+m*16+l15
    if (last) {
#pragma unroll
      for (int nb = 0; nb < 4; nb++)
#pragma unroll
        for (int m = 0; m < 2; m++)
#pragma unroll
          for (int r = 0; r < 4; r++) {
            int kvi = kv0 + nb * 16 + g * 4 + r;
            int qi = qw + m * 16 + l15;
            if (kvi > qi) accS[nb][m][r] = -1e30f;
          }
    }

    // ---- online softmax (row = lane's own q = m*16+l15), defer-max THR=8
#pragma unroll
    for (int m = 0; m < 2; m++) {
      float pmax = -1e30f;
#pragma unroll
      for (int nb = 0; nb < 4; nb++)
#pragma unroll
        for (int r = 0; r < 4; r++) pmax = fmaxf(pmax, accS[nb][m][r]);
      pmax = fmaxf(pmax, __shfl_xor(pmax, 16));
      pmax = fmaxf(pmax, __shfl_xor(pmax, 32));
      if (!__all(pmax <= mrun[m] + 8.0f)) {
        float mnew = fmaxf(mrun[m], pmax);
        float corr = __expf(mrun[m] - mnew);
        mrun[m] = mnew;
        lrun[m] *= corr;
        // rescale existing O rows (row q_local = g*4+r, state at l15=q_local)
#pragma unroll
        for (int r = 0; r < 4; r++) {
          float cr = __shfl(corr, (g << 4) + (g << 2) + r);
#pragma unroll
          for (int nd = 0; nd < 4; nd++) acco[m][nd][r] *= cr;
        }
      }
      float lsum = 0.f;
#pragma unroll
      for (int nb = 0; nb < 4; nb++) {
        bf16x4 pk;
#pragma unroll
        for (int r = 0; r < 4; r++) {
          float p = __expf(accS[nb][m][r] - mrun[m]);
          lsum += p;
          pk[r] = (__bf16)p;
        }
        *reinterpret_cast<bf16x4*>(&P_lds[w][m * 16 + l15][nb * 16 + g * 4]) = pk;
      }
      lsum += __shfl_xor(lsum, 16);
      lsum += __shfl_xor(lsum, 32);
      lrun[m] += lsum;
    }

    // ---- PV: O[q][d] += P[q][kv] * V[kv][d]
#pragma unroll
    for (int m = 0; m < 2; m++) {
      bf16x8 pa0 = *reinterpret_cast<const bf16x8*>(&P_lds[w][m * 16 + l15][g * 8]);
      bf16x8 pa1 = *reinterpret_cast<const bf16x8*>(&P_lds[w][m * 16 + l15][32 + g * 8]);
#pragma unroll
      for (int nd = 0; nd < 4; nd++) {
        acco[m][nd] = __builtin_amdgcn_mfma_f32_16x16x32_bf16(pa0, vb[nd][0], acco[m][nd], 0, 0, 0);
        acco[m][nd] = __builtin_amdgcn_mfma_f32_16x16x32_bf16(pa1, vb[nd][1], acco[m][nd], 0, 0, 0);
      }
    }

    // rotate prefetched K into place
    if (it + 1 < ntile) {
#pragma unroll
      for (int nb = 0; nb < 4; nb++) {
        kf[nb][0] = kn[nb][0];
        kf[nb][1] = kn[nb][1];
      }
    }
  }

  // epilogue: ctx = O / l
  __bf16* Cg = ctx + (size_t)b * SEQ * 1024 + h * 64;
#pragma unroll
  for (int m = 0; m < 2; m++) {
    float inv = 1.0f / lrun[m];
#pragma unroll
    for (int r = 0; r < 4; r++) {
      float ir = __shfl(inv, (g << 4) + (g << 2) + r);
      int qrow = qw + m * 16 + g * 4 + r;
#pragma unroll
      for (int nd = 0; nd < 4; nd++)
        Cg[(size_t)qrow * 1024 + nd * 16 + l15] = (__bf16)(acco[m][nd][r] * ir);
    }
  }
}

// ---------------------------------------------------------------------------
extern "C" void kernel_launch(void* const* d_in, const int* in_sizes, int n_in,
                              void* d_out, int out_size, void* d_ws, size_t ws_size,
                              hipStream_t stream) {
  const float* X  = (const float*)d_in[0];
  const float* Wq = (const float*)d_in[1];
  const float* Wk = (const float*)d_in[2];
  const float* Wv = (const float*)d_in[3];
  const float* Wo = (const float*)d_in[4];
  float* out = (float*)d_out;

  uint8_t* ws = (uint8_t*)d_ws;
  size_t off = 0;
  const size_t actBytes = (size_t)MROWS * 1024 * 2;          // 8 MB
  __bf16* Xb    = (__bf16*)(ws + off); off += actBytes;      // freed after QKV gemm
  __bf16* WqkvT = (__bf16*)(ws + off); off += (size_t)QKVN * 1024 * 2;
  __bf16* WoT   = (__bf16*)(ws + off); off += (size_t)1024 * 1024 * 2;
  __bf16* QKV   = (__bf16*)(ws + off); off += (size_t)MROWS * QKVN * 2;
  __bf16* Vt    = (__bf16*)(ws + off); off += actBytes;
  __bf16* Cb    = Xb;  // alias: X dead after QKV projection

  // 1) casts
  cast_f32_bf16<<<dim3(MROWS * 1024 / 4 / 256), dim3(256), 0, stream>>>(X, Xb, MROWS * 1024);
  transpose_cast<<<dim3(32, 32, 4), dim3(256), 0, stream>>>(Wq, Wk, Wv, Wo, WqkvT, WoT);

  // 2) fused QKV projection (Q pre-scaled by 1/8), 128x128 tiles
  gemm_bt<128, true, true><<<dim3(MROWS / 128, QKVN / 128), dim3(256), 0, stream>>>(
      Xb, WqkvT, QKV, MROWS, QKVN, EMB);

  // 3) V pre-transpose, then causal flash attention (barrier-free, XCD-local)
  v_transpose<<<dim3(SEQ / 64, BATCH * HEADS), dim3(256), 0, stream>>>(QKV, Vt);
  attn_fwd<<<dim3(256), dim3(512), 0, stream>>>(QKV, Vt, Cb);

  // 4) output projection (fp32 out), 128x128 tiles
  gemm_bt<128, false, false><<<dim3(MROWS / 128, PROJ / 128), dim3(256), 0, stream>>>(
      Cb, WoT, out, MROWS, PROJ, PROJ);
}